// Round 13
// baseline (188.222 us; speedup 1.0000x reference)
//
#include <hip/hip_runtime.h>
#include <hip/hip_bf16.h>
#include <math.h>

// Problem: B=2, T=2048, D_MODEL=1024, H=16, HD=64.
// I/O is FP32 (per reference dtypes); internal compute bf16 MFMA.
// Pipeline: k_prep (cvt weights + rope table + rmsnorm) ->
//   qkv gemm (bf16; ROPE fused on q/k, q pre-scaled by 0.125*log2e; V-blocks
//   write TRANSPOSED directly to vt) -> flash attn (out in-place over Q slot)
//   -> out gemm.
// Workspace (40MB): [qkv 24MB][xn 8MB][wqkvb 6MB][woutb 2MB].
// d_out (16.78MB) moonlights as scratch: tab = floats [0, 128K); vt = floats
// [2M, 4.19M) (8.39MB). Out-gemm overwrites all of d_out after attn reads vt.
//
// r13: XCD-clustered block mapping (T1): attn packs all 16 q-tiles of a head
// on one XCD (K/V becomes L2-resident, 2MB/XCD); out-gemm packs the 8 n-tiles
// of an A-panel on one XCD. Pure bijective index remaps, zero correctness risk.

typedef __bf16 bf16;
typedef __bf16 bf16x8 __attribute__((ext_vector_type(8)));
typedef __bf16 bf16x4 __attribute__((ext_vector_type(4)));
typedef float  f32x4  __attribute__((ext_vector_type(4)));
typedef unsigned u32x4 __attribute__((ext_vector_type(4)));

// async global->LDS, 16B per lane; LDS dest is wave-uniform base + lane*16
#define GLOAD16(g, l) __builtin_amdgcn_global_load_lds( \
    (const __attribute__((address_space(1))) void*)(g),  \
    (__attribute__((address_space(3))) void*)(l), 16, 0, 0)

__device__ __forceinline__ unsigned pk2(float a, float b) {
  unsigned short lo = __builtin_bit_cast(unsigned short, (bf16)a);
  unsigned short hi = __builtin_bit_cast(unsigned short, (bf16)b);
  return (unsigned)lo | ((unsigned)hi << 16);
}

// ---------------- fused prep: weight cvt (x2) + rope table + rmsnorm ----------------
// blocks [0,1536): cvt wqkv; [1536,2048): cvt wout; [2048,2304): rope table;
// [2304,6400): rmsnorm rows.
__global__ __launch_bounds__(256) void k_prep(
    const float* __restrict__ wqkv, const float* __restrict__ wout,
    const float* __restrict__ x, const float* __restrict__ w,
    bf16* __restrict__ wqkvb, bf16* __restrict__ woutb,
    bf16* __restrict__ xn, float2* __restrict__ tab) {
  const int bid = blockIdx.x, tid = threadIdx.x;
  if (bid < 2048) {            // weight cvt, 8 elems/thread
    const float* src = (bid < 1536) ? wqkv : wout;
    bf16* dst = (bid < 1536) ? wqkvb : woutb;
    int i = ((bid < 1536 ? bid : bid - 1536) * 256 + tid) * 8;
    float4 a = *(const float4*)(src + i);
    float4 b = *(const float4*)(src + i + 4);
    bf16x8 o;
    o[0] = (bf16)a.x; o[1] = (bf16)a.y; o[2] = (bf16)a.z; o[3] = (bf16)a.w;
    o[4] = (bf16)b.x; o[5] = (bf16)b.y; o[6] = (bf16)b.z; o[7] = (bf16)b.w;
    *(bf16x8*)(dst + i) = o;
    return;
  }
  if (bid < 2304) {            // rope cos/sin table: 2048 t x 32 j
    int idx = (bid - 2048) * 256 + tid;
    int t = idx >> 5, j = idx & 31;
    float invf = exp2f(-0.41524101186f * (float)j);   // 10000^(-2j/64)
    float th = (float)t * invf;
    float sn, cs;
    sincosf(th, &sn, &cs);
    tab[idx] = make_float2(cs, sn);
    return;
  }
  // rmsnorm: x[4096][1024] f32 -> xn bf16
  const int row = bid - 2304;
  float4 v = *(const float4*)(x + (size_t)row * 1024 + tid * 4);
  float ss = v.x * v.x + v.y * v.y + v.z * v.z + v.w * v.w;
  for (int m = 32; m >= 1; m >>= 1) ss += __shfl_xor(ss, m);
  __shared__ float red[4];
  if ((tid & 63) == 0) red[tid >> 6] = ss;
  __syncthreads();
  float ms = (red[0] + red[1] + red[2] + red[3]) * (1.f / 1024.f);
  float r = rsqrtf(ms + 1e-5f);
  float4 wv = *(const float4*)(w + tid * 4);
  bf16x4 o;
  o[0] = (bf16)(v.x * r * wv.x); o[1] = (bf16)(v.y * r * wv.y);
  o[2] = (bf16)(v.z * r * wv.z); o[3] = (bf16)(v.w * r * wv.w);
  *(bf16x4*)(xn + (size_t)row * 1024 + tid * 4) = o;
}

// ---------------- GEMM: C[M][N] = A[M][K](lda) @ B[N][K]^T, bf16 inputs ----------------
// RESID=0: C bf16.  RESID=1: C fp32, plus fp32 residual R.
// ROPE=1 (qkv gemm): n0<2048 blocks apply RoPE in-register (q slot additionally
//   scaled by 0.125*log2e -> attn's QK^T lands in exp2 domain). n0>=2048 blocks are
//   V blocks: epilogue LDS-transposes [c][r] and writes DIRECTLY to vt[bh][d][t].
// SWZ=1: 1D grid, XCD-clustered mapping -- all NBX n-tiles of one m-panel share
//   an XCD (A-panel L2-resident). SWZ=0: plain 2D grid.
// TM x 128 tile, BK=64, 4 waves 2x2, 16x16x32 bf16 MFMA, xor-swizzled LDS.
// LDS-read and global-staging offsets hoisted out of the k-loop (loop-invariant).
template<int RESID, int TM, int ROPE, int SWZ>
__global__ __launch_bounds__(256, (TM == 128) ? 3 : 2) void k_gemm_bt(
    const bf16* __restrict__ A, const bf16* __restrict__ B,
    const float* __restrict__ R, void* __restrict__ Cv,
    int M, int N, int K, int lda, const float2* __restrict__ tab,
    bf16* __restrict__ vtp) {
  constexpr int MT = TM / 32;            // m-tiles of 16 rows per wave (wave rows = TM/2)
  constexpr int PA = TM / 32;            // A staging chunks
  constexpr int AELEM = TM * 64;         // sA elems
  constexpr int SMEM = (AELEM + 8192 > TM * 136) ? (AELEM + 8192) : (TM * 136);
  const int tid = threadIdx.x;
  const int lane = tid & 63, L15 = lane & 15, quad = lane >> 4;
  const int wave = tid >> 6, wr = wave >> 1, wc = wave & 1;
  int n0, m0;
  if (SWZ) {   // 1D grid: xcd = bid&7; same-m0 blocks (sharing A panel) same XCD
    const int bid = blockIdx.x, xcd = bid & 7, s = bid >> 3;
    m0 = (xcd + 8 * (s & 7)) * TM;       // m-tile in [0,64)
    n0 = (s >> 3) * 128;                 // n-tile in [0,8)
  } else {
    n0 = blockIdx.x * 128; m0 = blockIdx.y * TM;
  }
  __shared__ __align__(16) bf16 smem[SMEM];   // sA(AELEM)+sB(8192); epilogue reuses as TMx136
  bf16* sA = smem; bf16* sB = smem + AELEM;
  f32x4 acc[MT][4];
  const f32x4 z = {0.f, 0.f, 0.f, 0.f};
  for (int i = 0; i < MT; i++) for (int j = 0; j < 4; j++) acc[i][j] = z;

  // hoisted loop-invariant offsets
  int aoff[2][MT], boff[2][4];
#pragma unroll
  for (int kk = 0; kk < 2; kk++) {
#pragma unroll
    for (int i = 0; i < MT; i++) {
      int ra = wr * (TM / 2) + i * 16 + L15;
      aoff[kk][i] = ra * 64 + (((kk * 4 + quad) ^ (ra & 7)) * 8);
    }
#pragma unroll
    for (int i = 0; i < 4; i++) {
      int rb = wc * 64 + i * 16 + L15;
      boff[kk][i] = rb * 64 + (((kk * 4 + quad) ^ (rb & 7)) * 8);
    }
  }
  int agl[PA], bgl[4];
#pragma unroll
  for (int p = 0; p < PA; p++) {
    int s = p * 256 + tid, r = s >> 3, c8 = (s & 7) ^ (r & 7);
    agl[p] = r * lda + c8 * 8;
  }
#pragma unroll
  for (int p = 0; p < 4; p++) {
    int s = p * 256 + tid, r = s >> 3, c8 = (s & 7) ^ (r & 7);
    bgl[p] = r * K + c8 * 8;
  }

  for (int k0 = 0; k0 < K; k0 += 64) {
    const bf16* Ab = A + (size_t)m0 * lda + k0;
    const bf16* Bb = B + (size_t)n0 * K + k0;
#pragma unroll
    for (int p = 0; p < PA; p++)
      GLOAD16(Ab + agl[p], sA + (p * 256 + tid) * 8);
#pragma unroll
    for (int p = 0; p < 4; p++)
      GLOAD16(Bb + bgl[p], sB + (p * 256 + tid) * 8);
    __syncthreads();
    for (int kk = 0; kk < 2; kk++) {
      bf16x8 af[MT], bfv[4];
      for (int i = 0; i < MT; i++) af[i] = *(const bf16x8*)(sA + aoff[kk][i]);
      for (int i = 0; i < 4; i++) bfv[i] = *(const bf16x8*)(sB + boff[kk][i]);
      __builtin_amdgcn_s_setprio(1);
      for (int mt = 0; mt < MT; mt++)
        for (int nt = 0; nt < 4; nt++)
          acc[mt][nt] = __builtin_amdgcn_mfma_f32_16x16x32_bf16(af[mt], bfv[nt], acc[mt][nt], 0, 0, 0);
      __builtin_amdgcn_s_setprio(0);
    }
    __syncthreads();
  }

  if (ROPE && (n0 >> 10) >= 2) {
    // ---- V block: transpose in LDS ([c][r]) and write straight to vt[bh][d][t] ----
    bf16* sC = smem;   // [128 c][136 r-pad]
    for (int mt = 0; mt < MT; mt++) for (int nt = 0; nt < 4; nt++) {
      int r = wr * (TM / 2) + mt * 16 + quad * 4, c = wc * 64 + nt * 16 + L15;
      f32x4 v = acc[mt][nt];
      bf16x4 u;
      u[0] = (bf16)v[0]; u[1] = (bf16)v[1]; u[2] = (bf16)v[2]; u[3] = (bf16)v[3];
      *(bf16x4*)(sC + c * 136 + r) = u;    // 4 consecutive t for fixed v-dim
    }
    __syncthreads();
    const int c = tid >> 1, sub = tid & 1;       // 2 threads per v-dim row, 64 t each
    const int cg = (n0 - 2048) + c;              // global v dim in [0,1024)
    const int h2 = cg >> 6, d = cg & 63;
    const size_t base = ((size_t)(m0 >> 11) * 16 + h2) * 131072
                      + (size_t)d * 2048 + (m0 & 2047) + sub * 64;
    const bf16* src = sC + c * 136 + sub * 64;
    for (int i = 0; i < 8; i++)
      *(bf16x8*)(vtp + base + i * 8) = *(const bf16x8*)(src + i * 8);
    return;
  }

  // fused RoPE on q/k slot blocks: rotate (dh, dh+32) pairs in f32 acc registers.
  if (ROPE) {
    const float qs = ((n0 >> 10) == 0) ? 0.18033688011f : 1.0f;  // q: 0.125*log2e
    const int tb = (m0 & 2047) + wr * (TM / 2);   // token of row base (b stripped)
    for (int mt = 0; mt < MT; mt++) {
      for (int nt = 0; nt < 2; nt++) {
        const int j = nt * 16 + L15;              // dh in [0,32)
        for (int g = 0; g < 4; g++) {
          int t = tb + mt * 16 + quad * 4 + g;
          float2 cs = tab[t * 32 + j];
          float lo = acc[mt][nt][g], hi = acc[mt][nt + 2][g];
          acc[mt][nt][g]     = (lo * cs.x - hi * cs.y) * qs;
          acc[mt][nt + 2][g] = (hi * cs.x + lo * cs.y) * qs;
        }
      }
    }
  }
  // epilogue: LDS transpose (bf16) for coalesced stores
  bf16* sC = smem;   // [TM][136]
  for (int mt = 0; mt < MT; mt++) for (int nt = 0; nt < 4; nt++) {
    int r = wr * (TM / 2) + mt * 16 + quad * 4, c = wc * 64 + nt * 16 + L15;
    f32x4 v = acc[mt][nt];
    for (int g = 0; g < 4; g++) sC[(r + g) * 136 + c] = (bf16)v[g];
  }
  __syncthreads();
  constexpr int TPR = 256 / TM;          // threads per output row
  constexpr int CPT = 128 / TPR;         // cols per thread
  const int rr = tid / TPR, sg = (tid % TPR) * CPT;
  const size_t row = (size_t)m0 + rr;
  const bf16* src = sC + rr * 136 + sg;
  if (RESID) {   // fp32 out + fp32 residual
    float* Cf = (float*)Cv;
    const float* rs = R + row * N + n0 + sg;
    float* dst = Cf + row * N + n0 + sg;
    for (int i = 0; i < CPT / 4; i++) {
      bf16x4 u = *(const bf16x4*)(src + i * 4);
      float4 rv = *(const float4*)(rs + i * 4);
      float4 o;
      o.x = (float)u[0] + rv.x; o.y = (float)u[1] + rv.y;
      o.z = (float)u[2] + rv.z; o.w = (float)u[3] + rv.w;
      *(float4*)(dst + i * 4) = o;
    }
  } else {       // bf16 out
    bf16* Cb = (bf16*)Cv;
    bf16* dst = Cb + row * N + n0 + sg;
    for (int i = 0; i < CPT / 8; i++)
      *(bf16x8*)(dst + i * 8) = *(const bf16x8*)(src + i * 8);
  }
}

// ---------------- Flash attention (bidirectional), S^T formulation ----------------
// 256 threads / 4 waves, each wave owns 32 q rows, full kv tile (LDS amortization).
// 1D grid 512 with XCD-clustered mapping: xcd = bid&7; all 16 q-tiles of a head
// land on one XCD -> that head's K/V (512KB) is L2-resident (4 heads = 2MB/XCD).
// Q pre-scaled by 0.125*log2e => QK^T in exp2 domain; fixed -M folded into MFMA
// C-init. Fixed-M softmax (M=5). exp2/pack interleaved into PV kc-groups.
// LDS-read offsets hoisted (koff/voff); single barrier per tile (STAGE after the
// top barrier; LDS reads of a buffer are MFMA-consumed before the next barrier).
// P exchange in-register (permlane32+16 swap); row-sum l via MFMA ones-trick.
// K/V double-buffered, counted vmcnt: prefetch in flight across the barrier.
__global__ __launch_bounds__(256, 2) void k_attn(bf16* __restrict__ qkv,
    const bf16* __restrict__ vt) {
  const int tid = threadIdx.x;
  const int lane = tid & 63, L15 = lane & 15, quad = lane >> 4;
  const int wave = tid >> 6;                   // 0..3, owns q rows wave*32..+31
  // XCD-clustered bijection: bid = xcd + 8*s; bh = xcd + 8*(s&3); qtile = s>>2
  const int bid = blockIdx.x, xcd = bid & 7, s = bid >> 3;
  const int bh = xcd + 8 * (s & 3);            // heads sharing this XCD's L2
  const int q0 = (s >> 2) * 128;
  const int b = bh >> 4, h = bh & 15;
  const bf16* Q  = qkv + (size_t)b * 2048 * 3072 + h * 64;           // + t*3072
  const bf16* Kg = qkv + (size_t)b * 2048 * 3072 + 1024 + h * 64;    // + t*3072
  const bf16* Vg = vt + (size_t)bh * 131072;                         // [d][2048]
  // double buffer: buf at smem + b*16384: sK[128][64] + sV[64][128], both swizzled
  __shared__ __align__(16) bf16 smem[32768];   // 64 KB

  bf16x8 qf[2][2];  // b-operand frags: Q[q][d] (pre-scaled), once per block
  for (int qt = 0; qt < 2; qt++) for (int kk = 0; kk < 2; kk++) {
    int rq = q0 + wave * 32 + qt * 16 + L15;
    qf[qt][kk] = *(const bf16x8*)(Q + (size_t)rq * 3072 + kk * 32 + quad * 8);
  }
  // hoisted loop-invariant LDS element offsets
  int koff[2][8], voff[4][4];
#pragma unroll
  for (int kk = 0; kk < 2; kk++)
    for (int kvt = 0; kvt < 8; kvt++) {
      int rk = kvt * 16 + L15;
      koff[kk][kvt] = rk * 64 + (((kk * 4 + quad) ^ (rk & 7)) * 8);
    }
#pragma unroll
  for (int kc = 0; kc < 4; kc++)
    for (int dt = 0; dt < 4; dt++) {
      int rd = dt * 16 + L15;
      int c = kc * 4 + quad;
      int cs = (c & 8) | ((c ^ (rd & 7)) & 7);
      voff[kc][dt] = rd * 128 + cs * 8;
    }
  f32x4 o[4][2];
  const f32x4 z = {0.f, 0.f, 0.f, 0.f};
  for (int i = 0; i < 4; i++) for (int j = 0; j < 2; j++) o[i][j] = z;
  f32x4 o5[2] = {z, z};                        // ones-trick row-sum accumulator
  const bf16 one = (bf16)1.0f;
  const bf16x8 ones8 = {one, one, one, one, one, one, one, one};
  const float mcl = 7.21347602f;               // 5.0 * log2(e): fixed-M shift
  const f32x4 minit = {-mcl, -mcl, -mcl, -mcl};

  // stage kv-tile kv0 into buffer at LDS offset `base` (8 global_load_lds / thread)
  auto STAGE = [&](int kv0, int base) {
    const bf16* Kb = Kg + (size_t)kv0 * 3072;
    bf16* sKb = smem + base;
    bf16* sVb = smem + base + 8192;
    for (int p = 0; p < 4; p++) {   // K: 128 rows x 8 chunks(16B)
      int s2 = p * 256 + tid, r = s2 >> 3, c8 = (s2 & 7) ^ (r & 7);
      GLOAD16(Kb + (size_t)r * 3072 + c8 * 8, sKb + s2 * 8);
    }
    for (int p = 0; p < 4; p++) {   // Vt: 64 rows x 16 chunks (xor low-3 bits)
      int s2 = p * 256 + tid, r = s2 >> 4, cl = s2 & 15;
      int c8 = (cl & 8) | ((cl ^ (r & 7)) & 7);
      GLOAD16(Vg + (size_t)r * 2048 + kv0 + c8 * 8, sVb + s2 * 8);
    }
  };

  STAGE(0, 0);                                 // prologue: tile 0
  for (int t = 0; t < 16; ++t) {
    const int cur = (t & 1) << 14;             // 0 / 16384
    // single barrier per tile: wait own tile-t loads, sync, then prefetch t+1
    asm volatile("s_waitcnt vmcnt(0)" ::: "memory");
    __builtin_amdgcn_s_barrier();              // all waves' tile-t stages visible;
                                               // also certifies buf^1 reads done
    __builtin_amdgcn_sched_barrier(0);
    if (t < 15) STAGE((t + 1) << 7, cur ^ 16384);  // in flight across compute(t)
    const bf16* sK = smem + cur;
    const bf16* sV = smem + cur + 8192;

    f32x4 st[8][2];
    {   // kk = 0: C-init = minit (folds the fixed -M shift; no zero-init pass)
      bf16x8 kf[8];
#pragma unroll
      for (int kvt = 0; kvt < 8; kvt++)
        kf[kvt] = *(const bf16x8*)(sK + koff[0][kvt]);
      __builtin_amdgcn_s_setprio(1);
#pragma unroll
      for (int kvt = 0; kvt < 8; kvt++)
        for (int qt = 0; qt < 2; qt++)
          st[kvt][qt] = __builtin_amdgcn_mfma_f32_16x16x32_bf16(kf[kvt], qf[qt][0], minit, 0, 0, 0);
      __builtin_amdgcn_s_setprio(0);
    }
    {   // kk = 1: accumulate
      bf16x8 kf[8];
#pragma unroll
      for (int kvt = 0; kvt < 8; kvt++)
        kf[kvt] = *(const bf16x8*)(sK + koff[1][kvt]);
      __builtin_amdgcn_s_setprio(1);
#pragma unroll
      for (int kvt = 0; kvt < 8; kvt++)
        for (int qt = 0; qt < 2; qt++)
          st[kvt][qt] = __builtin_amdgcn_mfma_f32_16x16x32_bf16(kf[kvt], qf[qt][1], st[kvt][qt], 0, 0, 0);
      __builtin_amdgcn_s_setprio(0);
    }
    // PV with INTERLEAVED fixed-M softmax: each kc-group computes exp2/pack for
    // its own kv pair (2kc, 2kc+1) just before the permlane+MFMA that consume it.
#pragma unroll
    for (int kc = 0; kc < 4; kc++) {
      bf16x8 vf[4];
#pragma unroll
      for (int dt = 0; dt < 4; dt++)
        vf[dt] = *(const bf16x8*)(sV + voff[kc][dt]);
      unsigned pA[2][2], pB[2][2];
#pragma unroll
      for (int qt = 0; qt < 2; qt++)
        for (int kq = 0; kq < 2; kq++) {
          const f32x4 s4 = st[2 * kc + kq][qt];
          float p0 = __builtin_amdgcn_exp2f(s4[0]);
          float p1 = __builtin_amdgcn_exp2f(s4[1]);
          float p2 = __builtin_amdgcn_exp2f(s4[2]);
          float p3 = __builtin_amdgcn_exp2f(s4[3]);
          pA[qt][kq] = pk2(p0, p1);
          pB[qt][kq] = pk2(p2, p3);
        }
#pragma unroll
      for (int qt = 0; qt < 2; qt++) {
        auto rA = __builtin_amdgcn_permlane32_swap(pA[qt][0], pA[qt][1], false, false);
        auto tAC = __builtin_amdgcn_permlane16_swap(rA[0], rA[1], false, false);
        auto rB = __builtin_amdgcn_permlane32_swap(pB[qt][0], pB[qt][1], false, false);
        auto tBD = __builtin_amdgcn_permlane16_swap(rB[0], rB[1], false, false);
        u32x4 pw;
        pw[0] = tAC[0]; pw[1] = tBD[0]; pw[2] = tAC[1]; pw[3] = tBD[1];
        bf16x8 pf = __builtin_bit_cast(bf16x8, pw);
        __builtin_amdgcn_s_setprio(1);
#pragma unroll
        for (int dt = 0; dt < 4; dt++)
          o[dt][qt] = __builtin_amdgcn_mfma_f32_16x16x32_bf16(vf[dt], pf, o[dt][qt], 0, 0, 0);
        o5[qt] = __builtin_amdgcn_mfma_f32_16x16x32_bf16(ones8, pf, o5[qt], 0, 0, 0);
        __builtin_amdgcn_s_setprio(0);
      }
    }
  }
  // ones-trick: every row of o5 tile = sum_k P => per-lane l in reg 0 (no shuffle)
  float invl[2] = {1.f / o5[0][0], 1.f / o5[1][0]};
  __syncthreads();               // all LDS reads of final buf consumed; reuse smem
  bf16* sO = smem;               // [128 q][72 d]
  for (int dt = 0; dt < 4; dt++) for (int qt = 0; qt < 2; qt++) {
    f32x4 v = o[dt][qt] * invl[qt];
    int ql = wave * 32 + qt * 16 + L15;
    uint2 w2; w2.x = pk2(v[0], v[1]); w2.y = pk2(v[2], v[3]);
    *(uint2*)(sO + ql * 72 + dt * 16 + quad * 4) = w2;  // regs = consecutive d
  }
  __syncthreads();
  const int rr = tid >> 1, sg = (tid & 1) * 32;
  const bf16* src = sO + rr * 72 + sg;
  bf16* dst = qkv + (size_t)(b * 2048 + q0 + rr) * 3072 + h * 64 + sg;  // Q slot, in place
  for (int i = 0; i < 4; i++)
    *(bf16x8*)(dst + i * 8) = *(const bf16x8*)(src + i * 8);
}

extern "C" void kernel_launch(void* const* d_in, const int* in_sizes, int n_in,
                              void* d_out, int out_size, void* d_ws, size_t ws_size,
                              hipStream_t stream) {
  (void)in_sizes; (void)n_in; (void)out_size;
  const float* x     = (const float*)d_in[0];   // fp32 per reference dtypes
  const float* normw = (const float*)d_in[1];
  const float* wqkv  = (const float*)d_in[2];
  const float* wout  = (const float*)d_in[3];
  float* out = (float*)d_out;
  bf16* ws  = (bf16*)d_ws;
  // 40MB workspace: [qkv 12M][xn 4M][wqkvb 3M][woutb 1M] bf16 elems
  const size_t NQKV = (size_t)4096 * 3072, NXN = (size_t)4096 * 1024;
  const size_t NWQ = (size_t)3072 * 1024, NWO = (size_t)1024 * 1024;
  const size_t need = (NQKV + NXN + NWQ + NWO) * sizeof(bf16);
  if (ws_size < need) return;   // debug signal: absmax ~= 4.97 => ws too small
  bf16* qkv    = ws;
  bf16* xn     = qkv + NQKV;
  bf16* wqkvb  = xn + NXN;
  bf16* woutb  = wqkvb + NWQ;
  float2* tab  = (float2*)out;                    // 512KB at d_out[0]
  bf16* vtp    = (bf16*)(out + 2097152);          // 8.39MB at d_out[8MB..16.78MB)
  // lifetimes: tab written by prep, read by qkv gemm; vt written by qkv gemm
  // V-blocks, read by attn; out gemm overwrites ALL of d_out last.
  k_prep<<<6400, 256, 0, stream>>>(wqkv, wout, x, normw, wqkvb, woutb, xn, tab);
  k_gemm_bt<0, 128, 1, 0><<<dim3(24, 32), 256, 0, stream>>>(xn, wqkvb, nullptr, qkv, 4096, 3072, 1024, 1024, tab, vtp);
  k_attn<<<512, 256, 0, stream>>>(qkv, vtp);
  k_gemm_bt<1, 64, 0, 1><<<512, 256, 0, stream>>>(qkv, woutb, x, out, 4096, 1024, 1024, 3072, nullptr, nullptr);
}

// Round 14
// 180.174 us; speedup vs baseline: 1.0447x; 1.0447x over previous
//
#include <hip/hip_runtime.h>
#include <hip/hip_bf16.h>
#include <math.h>

// Problem: B=2, T=2048, D_MODEL=1024, H=16, HD=64.
// I/O is FP32 (per reference dtypes); internal compute bf16 MFMA.
// Pipeline: k_prep (cvt weights + rope table + rmsnorm) ->
//   qkv gemm (bf16; ROPE fused on q/k, q pre-scaled by 0.125*log2e; V-blocks
//   write TRANSPOSED directly to vt) -> flash attn (out in-place over Q slot)
//   -> out gemm.
// Workspace (40MB): [qkv 24MB][xn 8MB][wqkvb 6MB][woutb 2MB].
// d_out (16.78MB) moonlights as scratch: tab = floats [0, 128K); vt = floats
// [2M, 4.19M) (8.39MB). Out-gemm overwrites all of d_out after attn reads vt.
//
// r14 (final): attn keeps the XCD-clustered 1D grid (r13: FETCH 69.7->12.35MB,
// -0.7us); out-gemm reverted to plain 2D grid (r13's SWZ remap cost ~5us).
// Attn structure = r9 local optimum (4 waves x 32q, dbuf + counted vmcnt,
// single barrier/tile); alternatives falsified in r3/r7/r11.

typedef __bf16 bf16;
typedef __bf16 bf16x8 __attribute__((ext_vector_type(8)));
typedef __bf16 bf16x4 __attribute__((ext_vector_type(4)));
typedef float  f32x4  __attribute__((ext_vector_type(4)));
typedef unsigned u32x4 __attribute__((ext_vector_type(4)));

// async global->LDS, 16B per lane; LDS dest is wave-uniform base + lane*16
#define GLOAD16(g, l) __builtin_amdgcn_global_load_lds( \
    (const __attribute__((address_space(1))) void*)(g),  \
    (__attribute__((address_space(3))) void*)(l), 16, 0, 0)

__device__ __forceinline__ unsigned pk2(float a, float b) {
  unsigned short lo = __builtin_bit_cast(unsigned short, (bf16)a);
  unsigned short hi = __builtin_bit_cast(unsigned short, (bf16)b);
  return (unsigned)lo | ((unsigned)hi << 16);
}

// ---------------- fused prep: weight cvt (x2) + rope table + rmsnorm ----------------
// blocks [0,1536): cvt wqkv; [1536,2048): cvt wout; [2048,2304): rope table;
// [2304,6400): rmsnorm rows.
__global__ __launch_bounds__(256) void k_prep(
    const float* __restrict__ wqkv, const float* __restrict__ wout,
    const float* __restrict__ x, const float* __restrict__ w,
    bf16* __restrict__ wqkvb, bf16* __restrict__ woutb,
    bf16* __restrict__ xn, float2* __restrict__ tab) {
  const int bid = blockIdx.x, tid = threadIdx.x;
  if (bid < 2048) {            // weight cvt, 8 elems/thread
    const float* src = (bid < 1536) ? wqkv : wout;
    bf16* dst = (bid < 1536) ? wqkvb : woutb;
    int i = ((bid < 1536 ? bid : bid - 1536) * 256 + tid) * 8;
    float4 a = *(const float4*)(src + i);
    float4 b = *(const float4*)(src + i + 4);
    bf16x8 o;
    o[0] = (bf16)a.x; o[1] = (bf16)a.y; o[2] = (bf16)a.z; o[3] = (bf16)a.w;
    o[4] = (bf16)b.x; o[5] = (bf16)b.y; o[6] = (bf16)b.z; o[7] = (bf16)b.w;
    *(bf16x8*)(dst + i) = o;
    return;
  }
  if (bid < 2304) {            // rope cos/sin table: 2048 t x 32 j
    int idx = (bid - 2048) * 256 + tid;
    int t = idx >> 5, j = idx & 31;
    float invf = exp2f(-0.41524101186f * (float)j);   // 10000^(-2j/64)
    float th = (float)t * invf;
    float sn, cs;
    sincosf(th, &sn, &cs);
    tab[idx] = make_float2(cs, sn);
    return;
  }
  // rmsnorm: x[4096][1024] f32 -> xn bf16
  const int row = bid - 2304;
  float4 v = *(const float4*)(x + (size_t)row * 1024 + tid * 4);
  float ss = v.x * v.x + v.y * v.y + v.z * v.z + v.w * v.w;
  for (int m = 32; m >= 1; m >>= 1) ss += __shfl_xor(ss, m);
  __shared__ float red[4];
  if ((tid & 63) == 0) red[tid >> 6] = ss;
  __syncthreads();
  float ms = (red[0] + red[1] + red[2] + red[3]) * (1.f / 1024.f);
  float r = rsqrtf(ms + 1e-5f);
  float4 wv = *(const float4*)(w + tid * 4);
  bf16x4 o;
  o[0] = (bf16)(v.x * r * wv.x); o[1] = (bf16)(v.y * r * wv.y);
  o[2] = (bf16)(v.z * r * wv.z); o[3] = (bf16)(v.w * r * wv.w);
  *(bf16x4*)(xn + (size_t)row * 1024 + tid * 4) = o;
}

// ---------------- GEMM: C[M][N] = A[M][K](lda) @ B[N][K]^T, bf16 inputs ----------------
// RESID=0: C bf16.  RESID=1: C fp32, plus fp32 residual R.
// ROPE=1 (qkv gemm): n0<2048 blocks apply RoPE in-register (q slot additionally
//   scaled by 0.125*log2e -> attn's QK^T lands in exp2 domain). n0>=2048 blocks are
//   V blocks: epilogue LDS-transposes [c][r] and writes DIRECTLY to vt[bh][d][t].
// TM x 128 tile, BK=64, 4 waves 2x2, 16x16x32 bf16 MFMA, xor-swizzled LDS.
// LDS-read and global-staging offsets hoisted out of the k-loop (loop-invariant).
template<int RESID, int TM, int ROPE>
__global__ __launch_bounds__(256, (TM == 128) ? 3 : 2) void k_gemm_bt(
    const bf16* __restrict__ A, const bf16* __restrict__ B,
    const float* __restrict__ R, void* __restrict__ Cv,
    int M, int N, int K, int lda, const float2* __restrict__ tab,
    bf16* __restrict__ vtp) {
  constexpr int MT = TM / 32;            // m-tiles of 16 rows per wave (wave rows = TM/2)
  constexpr int PA = TM / 32;            // A staging chunks
  constexpr int AELEM = TM * 64;         // sA elems
  constexpr int SMEM = (AELEM + 8192 > TM * 136) ? (AELEM + 8192) : (TM * 136);
  const int tid = threadIdx.x;
  const int lane = tid & 63, L15 = lane & 15, quad = lane >> 4;
  const int wave = tid >> 6, wr = wave >> 1, wc = wave & 1;
  const int n0 = blockIdx.x * 128, m0 = blockIdx.y * TM;
  __shared__ __align__(16) bf16 smem[SMEM];   // sA(AELEM)+sB(8192); epilogue reuses as TMx136
  bf16* sA = smem; bf16* sB = smem + AELEM;
  f32x4 acc[MT][4];
  const f32x4 z = {0.f, 0.f, 0.f, 0.f};
  for (int i = 0; i < MT; i++) for (int j = 0; j < 4; j++) acc[i][j] = z;

  // hoisted loop-invariant offsets
  int aoff[2][MT], boff[2][4];
#pragma unroll
  for (int kk = 0; kk < 2; kk++) {
#pragma unroll
    for (int i = 0; i < MT; i++) {
      int ra = wr * (TM / 2) + i * 16 + L15;
      aoff[kk][i] = ra * 64 + (((kk * 4 + quad) ^ (ra & 7)) * 8);
    }
#pragma unroll
    for (int i = 0; i < 4; i++) {
      int rb = wc * 64 + i * 16 + L15;
      boff[kk][i] = rb * 64 + (((kk * 4 + quad) ^ (rb & 7)) * 8);
    }
  }
  int agl[PA], bgl[4];
#pragma unroll
  for (int p = 0; p < PA; p++) {
    int s = p * 256 + tid, r = s >> 3, c8 = (s & 7) ^ (r & 7);
    agl[p] = r * lda + c8 * 8;
  }
#pragma unroll
  for (int p = 0; p < 4; p++) {
    int s = p * 256 + tid, r = s >> 3, c8 = (s & 7) ^ (r & 7);
    bgl[p] = r * K + c8 * 8;
  }

  for (int k0 = 0; k0 < K; k0 += 64) {
    const bf16* Ab = A + (size_t)m0 * lda + k0;
    const bf16* Bb = B + (size_t)n0 * K + k0;
#pragma unroll
    for (int p = 0; p < PA; p++)
      GLOAD16(Ab + agl[p], sA + (p * 256 + tid) * 8);
#pragma unroll
    for (int p = 0; p < 4; p++)
      GLOAD16(Bb + bgl[p], sB + (p * 256 + tid) * 8);
    __syncthreads();
    for (int kk = 0; kk < 2; kk++) {
      bf16x8 af[MT], bfv[4];
      for (int i = 0; i < MT; i++) af[i] = *(const bf16x8*)(sA + aoff[kk][i]);
      for (int i = 0; i < 4; i++) bfv[i] = *(const bf16x8*)(sB + boff[kk][i]);
      __builtin_amdgcn_s_setprio(1);
      for (int mt = 0; mt < MT; mt++)
        for (int nt = 0; nt < 4; nt++)
          acc[mt][nt] = __builtin_amdgcn_mfma_f32_16x16x32_bf16(af[mt], bfv[nt], acc[mt][nt], 0, 0, 0);
      __builtin_amdgcn_s_setprio(0);
    }
    __syncthreads();
  }

  if (ROPE && (n0 >> 10) >= 2) {
    // ---- V block: transpose in LDS ([c][r]) and write straight to vt[bh][d][t] ----
    bf16* sC = smem;   // [128 c][136 r-pad]
    for (int mt = 0; mt < MT; mt++) for (int nt = 0; nt < 4; nt++) {
      int r = wr * (TM / 2) + mt * 16 + quad * 4, c = wc * 64 + nt * 16 + L15;
      f32x4 v = acc[mt][nt];
      bf16x4 u;
      u[0] = (bf16)v[0]; u[1] = (bf16)v[1]; u[2] = (bf16)v[2]; u[3] = (bf16)v[3];
      *(bf16x4*)(sC + c * 136 + r) = u;    // 4 consecutive t for fixed v-dim
    }
    __syncthreads();
    const int c = tid >> 1, sub = tid & 1;       // 2 threads per v-dim row, 64 t each
    const int cg = (n0 - 2048) + c;              // global v dim in [0,1024)
    const int h2 = cg >> 6, d = cg & 63;
    const size_t base = ((size_t)(m0 >> 11) * 16 + h2) * 131072
                      + (size_t)d * 2048 + (m0 & 2047) + sub * 64;
    const bf16* src = sC + c * 136 + sub * 64;
    for (int i = 0; i < 8; i++)
      *(bf16x8*)(vtp + base + i * 8) = *(const bf16x8*)(src + i * 8);
    return;
  }

  // fused RoPE on q/k slot blocks: rotate (dh, dh+32) pairs in f32 acc registers.
  if (ROPE) {
    const float qs = ((n0 >> 10) == 0) ? 0.18033688011f : 1.0f;  // q: 0.125*log2e
    const int tb = (m0 & 2047) + wr * (TM / 2);   // token of row base (b stripped)
    for (int mt = 0; mt < MT; mt++) {
      for (int nt = 0; nt < 2; nt++) {
        const int j = nt * 16 + L15;              // dh in [0,32)
        for (int g = 0; g < 4; g++) {
          int t = tb + mt * 16 + quad * 4 + g;
          float2 cs = tab[t * 32 + j];
          float lo = acc[mt][nt][g], hi = acc[mt][nt + 2][g];
          acc[mt][nt][g]     = (lo * cs.x - hi * cs.y) * qs;
          acc[mt][nt + 2][g] = (hi * cs.x + lo * cs.y) * qs;
        }
      }
    }
  }
  // epilogue: LDS transpose (bf16) for coalesced stores
  bf16* sC = smem;   // [TM][136]
  for (int mt = 0; mt < MT; mt++) for (int nt = 0; nt < 4; nt++) {
    int r = wr * (TM / 2) + mt * 16 + quad * 4, c = wc * 64 + nt * 16 + L15;
    f32x4 v = acc[mt][nt];
    for (int g = 0; g < 4; g++) sC[(r + g) * 136 + c] = (bf16)v[g];
  }
  __syncthreads();
  constexpr int TPR = 256 / TM;          // threads per output row
  constexpr int CPT = 128 / TPR;         // cols per thread
  const int rr = tid / TPR, sg = (tid % TPR) * CPT;
  const size_t row = (size_t)m0 + rr;
  const bf16* src = sC + rr * 136 + sg;
  if (RESID) {   // fp32 out + fp32 residual
    float* Cf = (float*)Cv;
    const float* rs = R + row * N + n0 + sg;
    float* dst = Cf + row * N + n0 + sg;
    for (int i = 0; i < CPT / 4; i++) {
      bf16x4 u = *(const bf16x4*)(src + i * 4);
      float4 rv = *(const float4*)(rs + i * 4);
      float4 o;
      o.x = (float)u[0] + rv.x; o.y = (float)u[1] + rv.y;
      o.z = (float)u[2] + rv.z; o.w = (float)u[3] + rv.w;
      *(float4*)(dst + i * 4) = o;
    }
  } else {       // bf16 out
    bf16* Cb = (bf16*)Cv;
    bf16* dst = Cb + row * N + n0 + sg;
    for (int i = 0; i < CPT / 8; i++)
      *(bf16x8*)(dst + i * 8) = *(const bf16x8*)(src + i * 8);
  }
}

// ---------------- Flash attention (bidirectional), S^T formulation ----------------
// 256 threads / 4 waves, each wave owns 32 q rows, full kv tile (LDS amortization).
// 1D grid 512 with XCD-clustered mapping: xcd = bid&7; all 16 q-tiles of a head
// land on one XCD -> that head's K/V (512KB) is L2-resident (r13 measured:
// FETCH 69.7 -> 12.35MB, 5.6x).
// Q pre-scaled by 0.125*log2e => QK^T in exp2 domain; fixed -M folded into MFMA
// C-init. Fixed-M softmax (M=5). exp2/pack interleaved into PV kc-groups.
// LDS-read offsets hoisted (koff/voff); single barrier per tile (STAGE after the
// top barrier; LDS reads of a buffer are MFMA-consumed before the next barrier).
// P exchange in-register (permlane32+16 swap); row-sum l via MFMA ones-trick.
// K/V double-buffered, counted vmcnt: prefetch in flight across the barrier.
__global__ __launch_bounds__(256, 2) void k_attn(bf16* __restrict__ qkv,
    const bf16* __restrict__ vt) {
  const int tid = threadIdx.x;
  const int lane = tid & 63, L15 = lane & 15, quad = lane >> 4;
  const int wave = tid >> 6;                   // 0..3, owns q rows wave*32..+31
  // XCD-clustered bijection: bid = xcd + 8*s; bh = xcd + 8*(s&3); qtile = s>>2
  const int bid = blockIdx.x, xcd = bid & 7, s = bid >> 3;
  const int bh = xcd + 8 * (s & 3);            // heads sharing this XCD's L2
  const int q0 = (s >> 2) * 128;
  const int b = bh >> 4, h = bh & 15;
  const bf16* Q  = qkv + (size_t)b * 2048 * 3072 + h * 64;           // + t*3072
  const bf16* Kg = qkv + (size_t)b * 2048 * 3072 + 1024 + h * 64;    // + t*3072
  const bf16* Vg = vt + (size_t)bh * 131072;                         // [d][2048]
  // double buffer: buf at smem + b*16384: sK[128][64] + sV[64][128], both swizzled
  __shared__ __align__(16) bf16 smem[32768];   // 64 KB

  bf16x8 qf[2][2];  // b-operand frags: Q[q][d] (pre-scaled), once per block
  for (int qt = 0; qt < 2; qt++) for (int kk = 0; kk < 2; kk++) {
    int rq = q0 + wave * 32 + qt * 16 + L15;
    qf[qt][kk] = *(const bf16x8*)(Q + (size_t)rq * 3072 + kk * 32 + quad * 8);
  }
  // hoisted loop-invariant LDS element offsets
  int koff[2][8], voff[4][4];
#pragma unroll
  for (int kk = 0; kk < 2; kk++)
    for (int kvt = 0; kvt < 8; kvt++) {
      int rk = kvt * 16 + L15;
      koff[kk][kvt] = rk * 64 + (((kk * 4 + quad) ^ (rk & 7)) * 8);
    }
#pragma unroll
  for (int kc = 0; kc < 4; kc++)
    for (int dt = 0; dt < 4; dt++) {
      int rd = dt * 16 + L15;
      int c = kc * 4 + quad;
      int cs = (c & 8) | ((c ^ (rd & 7)) & 7);
      voff[kc][dt] = rd * 128 + cs * 8;
    }
  f32x4 o[4][2];
  const f32x4 z = {0.f, 0.f, 0.f, 0.f};
  for (int i = 0; i < 4; i++) for (int j = 0; j < 2; j++) o[i][j] = z;
  f32x4 o5[2] = {z, z};                        // ones-trick row-sum accumulator
  const bf16 one = (bf16)1.0f;
  const bf16x8 ones8 = {one, one, one, one, one, one, one, one};
  const float mcl = 7.21347602f;               // 5.0 * log2(e): fixed-M shift
  const f32x4 minit = {-mcl, -mcl, -mcl, -mcl};

  // stage kv-tile kv0 into buffer at LDS offset `base` (8 global_load_lds / thread)
  auto STAGE = [&](int kv0, int base) {
    const bf16* Kb = Kg + (size_t)kv0 * 3072;
    bf16* sKb = smem + base;
    bf16* sVb = smem + base + 8192;
    for (int p = 0; p < 4; p++) {   // K: 128 rows x 8 chunks(16B)
      int s2 = p * 256 + tid, r = s2 >> 3, c8 = (s2 & 7) ^ (r & 7);
      GLOAD16(Kb + (size_t)r * 3072 + c8 * 8, sKb + s2 * 8);
    }
    for (int p = 0; p < 4; p++) {   // Vt: 64 rows x 16 chunks (xor low-3 bits)
      int s2 = p * 256 + tid, r = s2 >> 4, cl = s2 & 15;
      int c8 = (cl & 8) | ((cl ^ (r & 7)) & 7);
      GLOAD16(Vg + (size_t)r * 2048 + kv0 + c8 * 8, sVb + s2 * 8);
    }
  };

  STAGE(0, 0);                                 // prologue: tile 0
  for (int t = 0; t < 16; ++t) {
    const int cur = (t & 1) << 14;             // 0 / 16384
    // single barrier per tile: wait own tile-t loads, sync, then prefetch t+1
    asm volatile("s_waitcnt vmcnt(0)" ::: "memory");
    __builtin_amdgcn_s_barrier();              // all waves' tile-t stages visible;
                                               // also certifies buf^1 reads done
    __builtin_amdgcn_sched_barrier(0);
    if (t < 15) STAGE((t + 1) << 7, cur ^ 16384);  // in flight across compute(t)
    const bf16* sK = smem + cur;
    const bf16* sV = smem + cur + 8192;

    f32x4 st[8][2];
    {   // kk = 0: C-init = minit (folds the fixed -M shift; no zero-init pass)
      bf16x8 kf[8];
#pragma unroll
      for (int kvt = 0; kvt < 8; kvt++)
        kf[kvt] = *(const bf16x8*)(sK + koff[0][kvt]);
      __builtin_amdgcn_s_setprio(1);
#pragma unroll
      for (int kvt = 0; kvt < 8; kvt++)
        for (int qt = 0; qt < 2; qt++)
          st[kvt][qt] = __builtin_amdgcn_mfma_f32_16x16x32_bf16(kf[kvt], qf[qt][0], minit, 0, 0, 0);
      __builtin_amdgcn_s_setprio(0);
    }
    {   // kk = 1: accumulate
      bf16x8 kf[8];
#pragma unroll
      for (int kvt = 0; kvt < 8; kvt++)
        kf[kvt] = *(const bf16x8*)(sK + koff[1][kvt]);
      __builtin_amdgcn_s_setprio(1);
#pragma unroll
      for (int kvt = 0; kvt < 8; kvt++)
        for (int qt = 0; qt < 2; qt++)
          st[kvt][qt] = __builtin_amdgcn_mfma_f32_16x16x32_bf16(kf[kvt], qf[qt][1], st[kvt][qt], 0, 0, 0);
      __builtin_amdgcn_s_setprio(0);
    }
    // PV with INTERLEAVED fixed-M softmax: each kc-group computes exp2/pack for
    // its own kv pair (2kc, 2kc+1) just before the permlane+MFMA that consume it.
#pragma unroll
    for (int kc = 0; kc < 4; kc++) {
      bf16x8 vf[4];
#pragma unroll
      for (int dt = 0; dt < 4; dt++)
        vf[dt] = *(const bf16x8*)(sV + voff[kc][dt]);
      unsigned pA[2][2], pB[2][2];
#pragma unroll
      for (int qt = 0; qt < 2; qt++)
        for (int kq = 0; kq < 2; kq++) {
          const f32x4 s4 = st[2 * kc + kq][qt];
          float p0 = __builtin_amdgcn_exp2f(s4[0]);
          float p1 = __builtin_amdgcn_exp2f(s4[1]);
          float p2 = __builtin_amdgcn_exp2f(s4[2]);
          float p3 = __builtin_amdgcn_exp2f(s4[3]);
          pA[qt][kq] = pk2(p0, p1);
          pB[qt][kq] = pk2(p2, p3);
        }
#pragma unroll
      for (int qt = 0; qt < 2; qt++) {
        auto rA = __builtin_amdgcn_permlane32_swap(pA[qt][0], pA[qt][1], false, false);
        auto tAC = __builtin_amdgcn_permlane16_swap(rA[0], rA[1], false, false);
        auto rB = __builtin_amdgcn_permlane32_swap(pB[qt][0], pB[qt][1], false, false);
        auto tBD = __builtin_amdgcn_permlane16_swap(rB[0], rB[1], false, false);
        u32x4 pw;
        pw[0] = tAC[0]; pw[1] = tBD[0]; pw[2] = tAC[1]; pw[3] = tBD[1];
        bf16x8 pf = __builtin_bit_cast(bf16x8, pw);
        __builtin_amdgcn_s_setprio(1);
#pragma unroll
        for (int dt = 0; dt < 4; dt++)
          o[dt][qt] = __builtin_amdgcn_mfma_f32_16x16x32_bf16(vf[dt], pf, o[dt][qt], 0, 0, 0);
        o5[qt] = __builtin_amdgcn_mfma_f32_16x16x32_bf16(ones8, pf, o5[qt], 0, 0, 0);
        __builtin_amdgcn_s_setprio(0);
      }
    }
  }
  // ones-trick: every row of o5 tile = sum_k P => per-lane l in reg 0 (no shuffle)
  float invl[2] = {1.f / o5[0][0], 1.f / o5[1][0]};
  __syncthreads();               // all LDS reads of final buf consumed; reuse smem
  bf16* sO = smem;               // [128 q][72 d]
  for (int dt = 0; dt < 4; dt++) for (int qt = 0; qt < 2; qt++) {
    f32x4 v = o[dt][qt] * invl[qt];
    int ql = wave * 32 + qt * 16 + L15;
    uint2 w2; w2.x = pk2(v[0], v[1]); w2.y = pk2(v[2], v[3]);
    *(uint2*)(sO + ql * 72 + dt * 16 + quad * 4) = w2;  // regs = consecutive d
  }
  __syncthreads();
  const int rr = tid >> 1, sg = (tid & 1) * 32;
  const bf16* src = sO + rr * 72 + sg;
  bf16* dst = qkv + (size_t)(b * 2048 + q0 + rr) * 3072 + h * 64 + sg;  // Q slot, in place
  for (int i = 0; i < 4; i++)
    *(bf16x8*)(dst + i * 8) = *(const bf16x8*)(src + i * 8);
}

extern "C" void kernel_launch(void* const* d_in, const int* in_sizes, int n_in,
                              void* d_out, int out_size, void* d_ws, size_t ws_size,
                              hipStream_t stream) {
  (void)in_sizes; (void)n_in; (void)out_size;
  const float* x     = (const float*)d_in[0];   // fp32 per reference dtypes
  const float* normw = (const float*)d_in[1];
  const float* wqkv  = (const float*)d_in[2];
  const float* wout  = (const float*)d_in[3];
  float* out = (float*)d_out;
  bf16* ws  = (bf16*)d_ws;
  // 40MB workspace: [qkv 12M][xn 4M][wqkvb 3M][woutb 1M] bf16 elems
  const size_t NQKV = (size_t)4096 * 3072, NXN = (size_t)4096 * 1024;
  const size_t NWQ = (size_t)3072 * 1024, NWO = (size_t)1024 * 1024;
  const size_t need = (NQKV + NXN + NWQ + NWO) * sizeof(bf16);
  if (ws_size < need) return;   // debug signal: absmax ~= 4.97 => ws too small
  bf16* qkv    = ws;
  bf16* xn     = qkv + NQKV;
  bf16* wqkvb  = xn + NXN;
  bf16* woutb  = wqkvb + NWQ;
  float2* tab  = (float2*)out;                    // 512KB at d_out[0]
  bf16* vtp    = (bf16*)(out + 2097152);          // 8.39MB at d_out[8MB..16.78MB)
  // lifetimes: tab written by prep, read by qkv gemm; vt written by qkv gemm
  // V-blocks, read by attn; out gemm overwrites ALL of d_out last.
  k_prep<<<6400, 256, 0, stream>>>(wqkv, wout, x, normw, wqkvb, woutb, xn, tab);
  k_gemm_bt<0, 128, 1><<<dim3(24, 32), 256, 0, stream>>>(xn, wqkvb, nullptr, qkv, 4096, 3072, 1024, 1024, tab, vtp);
  k_attn<<<512, 256, 0, stream>>>(qkv, vtp);
  k_gemm_bt<1, 64, 0><<<dim3(8, 64), 256, 0, stream>>>(qkv, woutb, x, out, 4096, 1024, 1024, 3072, nullptr, nullptr);
}